// Round 6
// baseline (854.047 us; speedup 1.0000x reference)
//
#include <hip/hip_runtime.h>
#include <hip/hip_bf16.h>

using short8 = __attribute__((ext_vector_type(8))) short;
using f32x16 = __attribute__((ext_vector_type(16))) float;
using us4    = __attribute__((ext_vector_type(4))) unsigned short;

#define NHID 15872

__device__ __forceinline__ unsigned short f2bf(float f) {
  unsigned u = __builtin_bit_cast(unsigned, f);
  u += 0x7fff + ((u >> 16) & 1);          // RNE
  return (unsigned short)(u >> 16);
}
__device__ __forceinline__ short f2bf_hw(float f) {
  __hip_bfloat16 h = __float2bfloat16(f); // HW cvt, pairs into v_cvt_pk_bf16_f32
  return __builtin_bit_cast(short, h);
}
__device__ __forceinline__ float bf2f(unsigned short h) {
  return __builtin_bit_cast(float, ((unsigned)h) << 16);
}

// ---------------- kernel 0: x fp32 -> bf16 ----------------
__global__ void cvt_x(const float* __restrict__ x, unsigned short* __restrict__ xb) {
  int i = (blockIdx.x * 256 + threadIdx.x) * 4;
  float4 v = *reinterpret_cast<const float4*>(x + i);
  us4 o;
  o[0] = f2bf(v.x); o[1] = f2bf(v.y); o[2] = f2bf(v.z); o[3] = f2bf(v.w);
  *reinterpret_cast<us4*>(xb + i) = o;
}

// ---------------- main GEMM v6: barrier-free streaming ----------------
// WG = 256 threads = 4 waves; wave w owns rows w*64..w*64+63, cols n0..n0+63.
// Per kstep (K=16): B-frags loaded DIRECTLY from global in MFMA layout
// (lane=col, 8 k's at stride NHID), f32->bf16 in-register. A-frags short8
// from L2. Depth-2 B ping-pong (named bufs). No LDS, no barriers.
// SWZ: 992 WGs, chunk=(bid&7)>>1 (XCD-affine), n=(bid>>3)*2+(bid&1).

#define LOADB16(R, S) do { \
    const float* bp_ = bbase + (size_t)(S) * 16 * NHID; \
    _Pragma("unroll") \
    for (int nb_ = 0; nb_ < 2; ++nb_) { \
      _Pragma("unroll") \
      for (int j_ = 0; j_ < 8; ++j_) \
        R[nb_ * 8 + j_] = bp_[(size_t)j_ * NHID + nb_ * 32]; \
    } \
  } while (0)

#define LOADA(S) do { \
    const unsigned short* ap_ = abase + (size_t)(S) * 16; \
    a0 = *reinterpret_cast<const short8*>(ap_); \
    a1 = *reinterpret_cast<const short8*>(ap_ + (size_t)32 * lda); \
  } while (0)

#define STEPM(R) do { \
    short8 b0_, b1_; \
    _Pragma("unroll") \
    for (int j_ = 0; j_ < 8; ++j_) { \
      b0_[j_] = f2bf_hw(R[j_]); \
      b1_[j_] = f2bf_hw(R[8 + j_]); \
    } \
    acc0 = __builtin_amdgcn_mfma_f32_32x32x16_bf16(a0, b0_, acc0, 0, 0, 0); \
    acc1 = __builtin_amdgcn_mfma_f32_32x32x16_bf16(a0, b1_, acc1, 0, 0, 0); \
    acc2 = __builtin_amdgcn_mfma_f32_32x32x16_bf16(a1, b0_, acc2, 0, 0, 0); \
    acc3 = __builtin_amdgcn_mfma_f32_32x32x16_bf16(a1, b1_, acc3, 0, 0, 0); \
  } while (0)

template<bool FINAL, bool SWZ>
__global__ __launch_bounds__(256, 4)
void gemm_v6(const unsigned short* __restrict__ A, int lda, int KC,
             const float* __restrict__ B, const float* __restrict__ bias,
             unsigned short* __restrict__ Cf, float* __restrict__ Cp)
{
  int nidx, ks0;
  if (SWZ) {
    int w_ = blockIdx.x;
    ks0  = (w_ & 7) >> 1;                 // 2 XCDs per K-chunk
    nidx = ((w_ >> 3) << 1) | (w_ & 1);   // 0..247
  } else {
    ks0 = blockIdx.y; nidx = blockIdx.x;
  }
  const int n0 = nidx * 64;
  const int k0 = ks0 * KC;
  const int tid  = threadIdx.x;
  const int w    = tid >> 6;
  const int lane = tid & 63;
  const int l31  = lane & 31;
  const int hi   = lane >> 5;
  const int m0   = w * 64;

  f32x16 acc0 = {}, acc1 = {}, acc2 = {}, acc3 = {};

  const unsigned short* abase = A + (size_t)(m0 + l31) * lda + k0 + hi * 8;
  const float* bbase = B + (size_t)(k0 + hi * 8) * NHID + n0 + l31;

  const int NK = KC >> 4;   // even for all our K (512->32, 3968->248, 15872->992)
  float bfA[16], bfB[16];
  short8 a0, a1;

  LOADB16(bfA, 0);
  for (int s = 0; s + 2 <= NK; s += 2) {
    LOADA(s);                 // A first: its wait never drains the B prefetch
    LOADB16(bfB, s + 1);
    STEPM(bfA);
    LOADA(s + 1);
    if (s + 2 < NK) LOADB16(bfA, s + 2);
    STEPM(bfB);
  }

  // epilogue: verified mapping col=n0+nb*32+l31, row=m0+mb*32+(reg&3)+8*(reg>>2)+4*hi
#define STOREC(ACC, MB, NB) do { \
    int col_ = n0 + (NB) * 32 + l31; \
    if (FINAL) { \
      float bv_ = bias[col_]; \
      _Pragma("unroll") \
      for (int reg_ = 0; reg_ < 16; ++reg_) { \
        int row_ = m0 + (MB) * 32 + (reg_ & 3) + 8 * (reg_ >> 2) + 4 * hi; \
        float v_ = ACC[reg_] + bv_; v_ = v_ > 0.f ? v_ : 0.f; \
        Cf[(size_t)row_ * NHID + col_] = f2bf(v_); \
      } \
    } else { \
      float* base_ = Cp + (size_t)ks0 * 256 * NHID; \
      _Pragma("unroll") \
      for (int reg_ = 0; reg_ < 16; ++reg_) { \
        int row_ = m0 + (MB) * 32 + (reg_ & 3) + 8 * (reg_ >> 2) + 4 * hi; \
        base_[(size_t)row_ * NHID + col_] = ACC[reg_]; \
      } \
    } \
  } while (0)

  STOREC(acc0, 0, 0);
  STOREC(acc1, 0, 1);
  STOREC(acc2, 1, 0);
  STOREC(acc3, 1, 1);
#undef STOREC
}

// ---------------- reduce K-split partials: h2 = relu(sum_s part + bias) -> bf16 ----------------
__global__ void reduce_h2(const float* __restrict__ part, const float* __restrict__ bias,
                          unsigned short* __restrict__ h2, int S) {
  size_t g = ((size_t)blockIdx.x * 256 + threadIdx.x) * 4;
  int c = (int)(g % NHID);
  float4 s = *reinterpret_cast<const float4*>(part + g);
  for (int k = 1; k < S; ++k) {
    float4 p = *reinterpret_cast<const float4*>(part + (size_t)k * 256 * NHID + g);
    s.x += p.x; s.y += p.y; s.z += p.z; s.w += p.w;
  }
  float4 b = *reinterpret_cast<const float4*>(bias + c);
  s.x += b.x; s.y += b.y; s.z += b.z; s.w += b.w;
  us4 o;
  o[0] = f2bf(s.x > 0.f ? s.x : 0.f);
  o[1] = f2bf(s.y > 0.f ? s.y : 0.f);
  o[2] = f2bf(s.z > 0.f ? s.z : 0.f);
  o[3] = f2bf(s.w > 0.f ? s.w : 0.f);
  *reinterpret_cast<us4*>(h2 + g) = o;
}

// ---------------- fold Wout [15872][992] -> Wv [15872][32] ----------------
__global__ void wv_fold(const float* __restrict__ Wout, float* __restrict__ Wv) {
  int g = blockIdx.x * 256 + threadIdx.x;
  int k = g >> 5, c = g & 31;
  const float* row = Wout + (size_t)k * 992;
  float s = 0.f;
#pragma unroll
  for (int o = 0; o < 32; ++o) {
    if (o == c) continue;
    int i = c < o ? c : o;
    int j = c < o ? o : c;
    int p = 31 * i - (i * (i - 1)) / 2 + (j - i - 1);
    s += row[2 * p + (c > o ? 1 : 0)];
  }
  Wv[g] = s;
}

// ---------------- votes partial = h2 @ Wv, K-split 32 ----------------
__global__ void votes_partial(const unsigned short* __restrict__ h2,
                              const float* __restrict__ Wv,
                              float* __restrict__ part) {
  int bm = blockIdx.x >> 5;
  int ks = blockIdx.x & 31;
  int r  = bm * 8 + (threadIdx.x >> 5);
  int c  = threadIdx.x & 31;
  const unsigned short* hrow = h2 + (size_t)r * NHID + ks * 496;
  const float* wp = Wv + (size_t)(ks * 496) * 32 + c;
  float s = 0.f;
  for (int k0 = 0; k0 < 496; k0 += 8) {
    short8 hv = *reinterpret_cast<const short8*>(hrow + k0);
#pragma unroll
    for (int j = 0; j < 8; ++j)
      s += bf2f((unsigned short)hv[j]) * wp[(size_t)(k0 + j) * 32];
  }
  part[(size_t)(ks * 256 + r) * 32 + c] = s;
}

// ---------------- reduce votes + bias-fold ----------------
__global__ void votes_reduce(const float* __restrict__ part,
                             const float* __restrict__ bout,
                             float* __restrict__ out) {
  int g = blockIdx.x * 256 + threadIdx.x;
  int c = g & 31;
  float s = 0.f;
#pragma unroll
  for (int ks = 0; ks < 32; ++ks) s += part[(size_t)ks * 8192 + g];
  float bv = 0.f;
#pragma unroll
  for (int o = 0; o < 32; ++o) {
    if (o == c) continue;
    int i = c < o ? c : o;
    int j = c < o ? o : c;
    int p = 31 * i - (i * (i - 1)) / 2 + (j - i - 1);
    bv += bout[2 * p + (c > o ? 1 : 0)];
  }
  out[g] = s + bv;
}

extern "C" void kernel_launch(void* const* d_in, const int* in_sizes, int n_in,
                              void* d_out, int out_size, void* d_ws, size_t ws_size,
                              hipStream_t stream) {
  const float* x    = (const float*)d_in[0];
  const float* W1   = (const float*)d_in[1];
  const float* b1   = (const float*)d_in[2];
  const float* W2   = (const float*)d_in[3];
  const float* b2   = (const float*)d_in[4];
  const float* Wout = (const float*)d_in[5];
  const float* bout = (const float*)d_in[6];
  float* out = (float*)d_out;

  char* ws = (char*)d_ws;
  unsigned short* xb = (unsigned short*)(ws);                       // 262144
  unsigned short* h1 = (unsigned short*)(ws + 262144);              // 8126464
  unsigned short* h2 = (unsigned short*)(ws + 8388608);             // 8126464
  float*          Wv = (float*)(ws + 16515072);                     // 2031616
  float*        part = (float*)(ws + 18546688);                     // 1048576
  float*       part2 = (float*)(ws + 19595264);                     // 4*256*NHID*4

  const size_t PART1 = (size_t)256 * NHID * 4;
  const bool split4 = ws_size >= 19595264ull + 4 * PART1;

  hipLaunchKernelGGL(cvt_x, dim3(128), dim3(256), 0, stream, x, xb);
  hipLaunchKernelGGL((gemm_v6<true, false>), dim3(248, 1), dim3(256), 0, stream,
                     xb, 512, 512, W1, b1, h1, (float*)nullptr);
  if (split4) {
    hipLaunchKernelGGL((gemm_v6<false, true>), dim3(992), dim3(256), 0, stream,
                       h1, NHID, NHID / 4, W2, (const float*)nullptr,
                       (unsigned short*)nullptr, part2);
    hipLaunchKernelGGL(reduce_h2, dim3(3968), dim3(256), 0, stream, part2, b2, h2, 4);
  } else {
    hipLaunchKernelGGL((gemm_v6<true, false>), dim3(248, 1), dim3(256), 0, stream,
                       h1, NHID, NHID, W2, b2, h2, (float*)nullptr);
  }
  hipLaunchKernelGGL(wv_fold,       dim3(1984), dim3(256), 0, stream, Wout, Wv);
  hipLaunchKernelGGL(votes_partial, dim3(1024), dim3(256), 0, stream, h2, Wv, part);
  hipLaunchKernelGGL(votes_reduce,  dim3(32),   dim3(256), 0, stream, part, bout, out);
}

// Round 7
// 819.285 us; speedup vs baseline: 1.0424x; 1.0424x over previous
//
#include <hip/hip_runtime.h>
#include <hip/hip_bf16.h>

using short8 = __attribute__((ext_vector_type(8))) short;
using f32x16 = __attribute__((ext_vector_type(16))) float;
using us4    = __attribute__((ext_vector_type(4))) unsigned short;

#define NHID 15872

__device__ __forceinline__ unsigned short f2bf(float f) {
  unsigned u = __builtin_bit_cast(unsigned, f);
  u += 0x7fff + ((u >> 16) & 1);          // RNE
  return (unsigned short)(u >> 16);
}
__device__ __forceinline__ short f2bf_hw(float f) {
  __hip_bfloat16 h = __float2bfloat16(f); // HW cvt, pairs into v_cvt_pk_bf16_f32
  return __builtin_bit_cast(short, h);
}
__device__ __forceinline__ float bf2f(unsigned short h) {
  return __builtin_bit_cast(float, ((unsigned)h) << 16);
}

// async global->LDS, 16B per lane. LDS dest: wave-uniform base + lane*16.
__device__ __forceinline__ void gload16(const void* g, void* l) {
  __builtin_amdgcn_global_load_lds(
      (const __attribute__((address_space(1))) unsigned int*)g,
      (__attribute__((address_space(3))) unsigned int*)l, 16, 0, 0);
}

// ---------------- kernel 0: x fp32 -> bf16 ----------------
__global__ void cvt_x(const float* __restrict__ x, unsigned short* __restrict__ xb) {
  int i = (blockIdx.x * 256 + threadIdx.x) * 4;
  float4 v = *reinterpret_cast<const float4*>(x + i);
  us4 o;
  o[0] = f2bf(v.x); o[1] = f2bf(v.y); o[2] = f2bf(v.z); o[3] = f2bf(v.w);
  *reinterpret_cast<us4*>(xb + i) = o;
}

// ---------------- main GEMM v7 ----------------
// BM=256, BN=64, BK=64. WG = 256 thr = 4 waves (2M x 2N): wave (wm,wn) owns
// rows wm*128..+127 (4 row-blocks), cols n0+wn*32..+31.
// B staged fp32 via global_load_lds (width 16) into LINEAR LDS [k][64col],
// double-buffered (2x16KB). bf16 cvt at frag-read (v_cvt_pk). A-frags direct
// from global (L1/L2-hot). 4 WG/CU -> 4 independent HBM streams.

// stage: thread covers k=(tid>>4)+c*16, col4=(tid&15)*4; LDS off = c*1024+w*256+lane*4
#define STAGE(BUF, T) do { _Pragma("unroll") \
  for (int c_ = 0; c_ < 4; ++c_) \
    gload16(gstage + ((size_t)(T) * 64 + c_ * 16) * NHID, \
            &Blds[BUF][c_ * 1024 + w * 256]); \
} while (0)

#define COMPUTE(BUF, T) do { \
  short8 bfr_[4]; \
  _Pragma("unroll") \
  for (int ks_ = 0; ks_ < 4; ++ks_) { \
    const float* fb_ = &Blds[BUF][(ks_ * 16 + hi * 8) * 64 + fcol]; \
    float tf_[8]; \
    _Pragma("unroll") \
    for (int j_ = 0; j_ < 8; ++j_) tf_[j_] = fb_[j_ * 64]; \
    _Pragma("unroll") \
    for (int j_ = 0; j_ < 8; ++j_) bfr_[ks_][j_] = f2bf_hw(tf_[j_]); \
  } \
  _Pragma("unroll") \
  for (int rb_ = 0; rb_ < 4; ++rb_) { \
    const unsigned short* ap_ = arow + (size_t)rb_ * 32 * lda + (size_t)(T) * 64; \
    short8 a0_ = *reinterpret_cast<const short8*>(ap_); \
    short8 a1_ = *reinterpret_cast<const short8*>(ap_ + 16); \
    short8 a2_ = *reinterpret_cast<const short8*>(ap_ + 32); \
    short8 a3_ = *reinterpret_cast<const short8*>(ap_ + 48); \
    acc[rb_] = __builtin_amdgcn_mfma_f32_32x32x16_bf16(a0_, bfr_[0], acc[rb_], 0, 0, 0); \
    acc[rb_] = __builtin_amdgcn_mfma_f32_32x32x16_bf16(a1_, bfr_[1], acc[rb_], 0, 0, 0); \
    acc[rb_] = __builtin_amdgcn_mfma_f32_32x32x16_bf16(a2_, bfr_[2], acc[rb_], 0, 0, 0); \
    acc[rb_] = __builtin_amdgcn_mfma_f32_32x32x16_bf16(a3_, bfr_[3], acc[rb_], 0, 0, 0); \
  } \
} while (0)

template<bool FINAL, bool SWZ>
__global__ __launch_bounds__(256, 4)
void gemm_v7(const unsigned short* __restrict__ A, int lda, int KC,
             const float* __restrict__ B, const float* __restrict__ bias,
             unsigned short* __restrict__ Cf, float* __restrict__ Cp)
{
  __shared__ float Blds[2][64 * 64];   // [buf][k][col] fp32, LINEAR
  int nidx, ks0;
  if (SWZ) {
    int b = blockIdx.x;
    ks0  = (b & 7) >> 1;                 // 2 XCDs per K-chunk
    nidx = ((b >> 3) << 1) | (b & 1);    // 0..247
  } else {
    ks0 = blockIdx.y; nidx = blockIdx.x;
  }
  const int n0   = nidx * 64;
  const int k0   = ks0 * KC;
  const int tid  = threadIdx.x;
  const int w    = tid >> 6;
  const int lane = tid & 63;
  const int l31  = lane & 31;
  const int hi   = lane >> 5;
  const int wm   = w >> 1;     // rows wm*128..+127
  const int wn   = w & 1;      // cols wn*32..+31

  f32x16 acc[4] = {};

  const float* gstage = B + (size_t)(k0 + (tid >> 4)) * NHID + n0 + (tid & 15) * 4;
  const int fcol = wn * 32 + l31;
  const unsigned short* arow = A + (size_t)(wm * 128 + l31) * lda + k0 + hi * 8;

  const int NT = KC >> 6;

  STAGE(0, 0);
  __syncthreads();
  int cur = 0;
  for (int t = 0; t < NT; ++t) {
    if (t + 1 < NT) STAGE(cur ^ 1, t + 1);   // issue next-tile DMA early
    COMPUTE(cur, t);
    __syncthreads();                          // drains DMA; other WGs cover HBM
    cur ^= 1;
  }

  // epilogue: verified mapping col=lane&31, row=(reg&3)+8*(reg>>2)+4*hi
  const int col = n0 + wn * 32 + l31;
#pragma unroll
  for (int rb = 0; rb < 4; ++rb) {
    if (FINAL) {
      float bv = bias[col];
#pragma unroll
      for (int reg = 0; reg < 16; ++reg) {
        int row = wm * 128 + rb * 32 + (reg & 3) + 8 * (reg >> 2) + 4 * hi;
        float v = acc[rb][reg] + bv; v = v > 0.f ? v : 0.f;
        Cf[(size_t)row * NHID + col] = f2bf(v);
      }
    } else {
      float* base = Cp + (size_t)ks0 * 256 * NHID;
#pragma unroll
      for (int reg = 0; reg < 16; ++reg) {
        int row = wm * 128 + rb * 32 + (reg & 3) + 8 * (reg >> 2) + 4 * hi;
        base[(size_t)row * NHID + col] = acc[rb][reg];
      }
    }
  }
}

// ---------------- reduce K-split partials: h2 = relu(sum_s part + bias) -> bf16 ----------------
__global__ void reduce_h2(const float* __restrict__ part, const float* __restrict__ bias,
                          unsigned short* __restrict__ h2, int S) {
  size_t g = ((size_t)blockIdx.x * 256 + threadIdx.x) * 4;
  int c = (int)(g % NHID);
  float4 s = *reinterpret_cast<const float4*>(part + g);
  for (int k = 1; k < S; ++k) {
    float4 p = *reinterpret_cast<const float4*>(part + (size_t)k * 256 * NHID + g);
    s.x += p.x; s.y += p.y; s.z += p.z; s.w += p.w;
  }
  float4 b = *reinterpret_cast<const float4*>(bias + c);
  s.x += b.x; s.y += b.y; s.z += b.z; s.w += b.w;
  us4 o;
  o[0] = f2bf(s.x > 0.f ? s.x : 0.f);
  o[1] = f2bf(s.y > 0.f ? s.y : 0.f);
  o[2] = f2bf(s.z > 0.f ? s.z : 0.f);
  o[3] = f2bf(s.w > 0.f ? s.w : 0.f);
  *reinterpret_cast<us4*>(h2 + g) = o;
}

// ---------------- fold Wout [15872][992] -> Wv [15872][32] ----------------
__global__ void wv_fold(const float* __restrict__ Wout, float* __restrict__ Wv) {
  int g = blockIdx.x * 256 + threadIdx.x;
  int k = g >> 5, c = g & 31;
  const float* row = Wout + (size_t)k * 992;
  float s = 0.f;
#pragma unroll
  for (int o = 0; o < 32; ++o) {
    if (o == c) continue;
    int i = c < o ? c : o;
    int j = c < o ? o : c;
    int p = 31 * i - (i * (i - 1)) / 2 + (j - i - 1);
    s += row[2 * p + (c > o ? 1 : 0)];
  }
  Wv[g] = s;
}

// ---------------- votes partial = h2 @ Wv, K-split 32 ----------------
__global__ void votes_partial(const unsigned short* __restrict__ h2,
                              const float* __restrict__ Wv,
                              float* __restrict__ part) {
  int bm = blockIdx.x >> 5;
  int ks = blockIdx.x & 31;
  int r  = bm * 8 + (threadIdx.x >> 5);
  int c  = threadIdx.x & 31;
  const unsigned short* hrow = h2 + (size_t)r * NHID + ks * 496;
  const float* wp = Wv + (size_t)(ks * 496) * 32 + c;
  float s = 0.f;
  for (int k0 = 0; k0 < 496; k0 += 8) {
    short8 hv = *reinterpret_cast<const short8*>(hrow + k0);
#pragma unroll
    for (int j = 0; j < 8; ++j)
      s += bf2f((unsigned short)hv[j]) * wp[(size_t)(k0 + j) * 32];
  }
  part[(size_t)(ks * 256 + r) * 32 + c] = s;
}

// ---------------- reduce votes + bias-fold ----------------
__global__ void votes_reduce(const float* __restrict__ part,
                             const float* __restrict__ bout,
                             float* __restrict__ out) {
  int g = blockIdx.x * 256 + threadIdx.x;
  int c = g & 31;
  float s = 0.f;
#pragma unroll
  for (int ks = 0; ks < 32; ++ks) s += part[(size_t)ks * 8192 + g];
  float bv = 0.f;
#pragma unroll
  for (int o = 0; o < 32; ++o) {
    if (o == c) continue;
    int i = c < o ? c : o;
    int j = c < o ? o : c;
    int p = 31 * i - (i * (i - 1)) / 2 + (j - i - 1);
    bv += bout[2 * p + (c > o ? 1 : 0)];
  }
  out[g] = s + bv;
}

extern "C" void kernel_launch(void* const* d_in, const int* in_sizes, int n_in,
                              void* d_out, int out_size, void* d_ws, size_t ws_size,
                              hipStream_t stream) {
  const float* x    = (const float*)d_in[0];
  const float* W1   = (const float*)d_in[1];
  const float* b1   = (const float*)d_in[2];
  const float* W2   = (const float*)d_in[3];
  const float* b2   = (const float*)d_in[4];
  const float* Wout = (const float*)d_in[5];
  const float* bout = (const float*)d_in[6];
  float* out = (float*)d_out;

  char* ws = (char*)d_ws;
  unsigned short* xb = (unsigned short*)(ws);                       // 262144
  unsigned short* h1 = (unsigned short*)(ws + 262144);              // 8126464
  unsigned short* h2 = (unsigned short*)(ws + 8388608);             // 8126464
  float*          Wv = (float*)(ws + 16515072);                     // 2031616
  float*        part = (float*)(ws + 18546688);                     // 1048576
  float*       part2 = (float*)(ws + 19595264);                     // 4*256*NHID*4

  const size_t PART1 = (size_t)256 * NHID * 4;
  const bool split4 = ws_size >= 19595264ull + 4 * PART1;

  hipLaunchKernelGGL(cvt_x, dim3(128), dim3(256), 0, stream, x, xb);
  hipLaunchKernelGGL((gemm_v7<true, false>), dim3(248, 1), dim3(256), 0, stream,
                     xb, 512, 512, W1, b1, h1, (float*)nullptr);
  if (split4) {
    hipLaunchKernelGGL((gemm_v7<false, true>), dim3(992), dim3(256), 0, stream,
                       h1, NHID, NHID / 4, W2, (const float*)nullptr,
                       (unsigned short*)nullptr, part2);
    hipLaunchKernelGGL(reduce_h2, dim3(3968), dim3(256), 0, stream, part2, b2, h2, 4);
  } else {
    hipLaunchKernelGGL((gemm_v7<true, false>), dim3(248, 1), dim3(256), 0, stream,
                       h1, NHID, NHID, W2, b2, h2, (float*)nullptr);
  }
  hipLaunchKernelGGL(wv_fold,       dim3(1984), dim3(256), 0, stream, Wout, Wv);
  hipLaunchKernelGGL(votes_partial, dim3(1024), dim3(256), 0, stream, h2, Wv, part);
  hipLaunchKernelGGL(votes_reduce,  dim3(32),   dim3(256), 0, stream, part, bout, out);
}

// Round 8
// 491.294 us; speedup vs baseline: 1.7384x; 1.6676x over previous
//
#include <hip/hip_runtime.h>
#include <hip/hip_bf16.h>

using short8 = __attribute__((ext_vector_type(8))) short;
using f32x16 = __attribute__((ext_vector_type(16))) float;
using us4    = __attribute__((ext_vector_type(4))) unsigned short;

#define NHID 15872

__device__ __forceinline__ unsigned short f2bf(float f) {
  unsigned u = __builtin_bit_cast(unsigned, f);
  u += 0x7fff + ((u >> 16) & 1);          // RNE
  return (unsigned short)(u >> 16);
}
__device__ __forceinline__ short f2bf_hw(float f) {
  __hip_bfloat16 h = __float2bfloat16(f); // HW cvt, pairs into v_cvt_pk_bf16_f32
  return __builtin_bit_cast(short, h);
}
__device__ __forceinline__ float bf2f(unsigned short h) {
  return __builtin_bit_cast(float, ((unsigned)h) << 16);
}

// async global->LDS, 16B/lane. LDS dest = wave-uniform base + lane*16; global src per-lane.
__device__ __forceinline__ void gload16(const void* g, void* l) {
  __builtin_amdgcn_global_load_lds(
      (const __attribute__((address_space(1))) unsigned int*)g,
      (__attribute__((address_space(3))) unsigned int*)l, 16, 0, 0);
}

// ---------------- kernel 0: x fp32 -> bf16 ----------------
__global__ void cvt_x(const float* __restrict__ x, unsigned short* __restrict__ xb) {
  int i = (blockIdx.x * 256 + threadIdx.x) * 4;
  float4 v = *reinterpret_cast<const float4*>(x + i);
  us4 o;
  o[0] = f2bf(v.x); o[1] = f2bf(v.y); o[2] = f2bf(v.z); o[3] = f2bf(v.w);
  *reinterpret_cast<us4*>(xb + i) = o;
}

// ---------------- main GEMM v8 ----------------
// BM=256 (all M), BN=256, BK=32. 512 thr = 8 waves; wave w owns cols w*32..+31
// and ALL 256 rows (acc = 8 x f32x16 = 128 regs/lane). 1 WG/CU.
// B: [32k][256col] fp32 LDS via gload16 — ONE WAVE-INSTR = 1 KB CONTIGUOUS
//    (64 lanes x 16 B spanning a full 256-col row) -> large DRAM chunks.
// A: [2 kh][256row x 8k] bf16 LDS via gload16 (L2-hot re-read).
// Compute reads ONLY LDS -> vmcnt carries just the prefetch, drained once at
// the barrier with a full compute-phase of slack.

// B stage: issue j: k_local=j*8+w, lane covers cols lane*4..+3 (16 B)
#define STAGE(BUF, T) do { \
    _Pragma("unroll") \
    for (int j_ = 0; j_ < 4; ++j_) \
      gload16(bsrc + ((size_t)(T) * 32 + j_ * 8) * NHID, \
              &Blds[BUF][(j_ * 8 + w) * 256]); \
    _Pragma("unroll") \
    for (int i_ = 0; i_ < 2; ++i_) \
      gload16(asrc + (size_t)(T) * 32 + i_ * 16, \
              &Alds[BUF][i_ * 4096 + w * 512]); \
  } while (0)

#define COMPUTE(BUF) do { \
    _Pragma("unroll") \
    for (int ks_ = 0; ks_ < 2; ++ks_) { \
      float bf_[8]; \
      _Pragma("unroll") \
      for (int jj_ = 0; jj_ < 8; ++jj_) \
        bf_[jj_] = Blds[BUF][(ks_ * 16 + hi * 8 + jj_) * 256 + w * 32 + l31]; \
      short8 bfr_; \
      _Pragma("unroll") \
      for (int jj_ = 0; jj_ < 8; ++jj_) bfr_[jj_] = f2bf_hw(bf_[jj_]); \
      _Pragma("unroll") \
      for (int rb_ = 0; rb_ < 8; ++rb_) { \
        short8 afr_ = *reinterpret_cast<const short8*>( \
            &Alds[BUF][ks_ * 4096 + (rb_ * 32 + l31 + 256 * hi) * 8]); \
        acc[rb_] = __builtin_amdgcn_mfma_f32_32x32x16_bf16(afr_, bfr_, acc[rb_], 0, 0, 0); \
      } \
    } \
  } while (0)

template<bool FINAL>
__global__ __launch_bounds__(512, 2)
void gemm_v8(const unsigned short* __restrict__ A, int lda, int KC,
             const float* __restrict__ B, const float* __restrict__ bias,
             unsigned short* __restrict__ Cf, float* __restrict__ Cp)
{
  __shared__ float Blds[2][32 * 256];   // 64 KB: [buf][k][col] fp32, linear
  __shared__ short Alds[2][2 * 4096];   // 32 KB: [buf][kh][row*8k] bf16, linear

  const int n0   = blockIdx.x * 256;
  const int ks0  = blockIdx.y;
  const int k0   = ks0 * KC;
  const int tid  = threadIdx.x;
  const int w    = tid >> 6;          // wave 0..7
  const int lane = tid & 63;
  const int l31  = lane & 31;
  const int hi   = lane >> 5;

  f32x16 acc[8] = {};

  // B src: lane covers 16 B of row (k0 + j*8 + w), cols n0 + lane*4..+3
  const float* bsrc = B + (size_t)(k0 + w) * NHID + n0 + lane * 4;
  // A src: thread covers row tid&255, k-bytes (tid>>8)*8 within each 16-k half
  const unsigned short* asrc = A + (size_t)(tid & 255) * lda + k0 + (tid >> 8) * 8;

  const int NT = KC >> 5;

  STAGE(0, 0);
  __syncthreads();
  int cur = 0;
  for (int t = 0; t < NT; ++t) {
    if (t + 1 < NT) STAGE(cur ^ 1, t + 1);   // prefetch next tile (vmcnt only)
    COMPUTE(cur);                            // LDS-only (lgkmcnt)
    __syncthreads();                         // single vmcnt(0) drain point
    cur ^= 1;
  }

  // epilogue: verified mapping col = base + l31, row = rb*32 + (reg&3)+8*(reg>>2)+4*hi
  const int col = n0 + w * 32 + l31;
#pragma unroll
  for (int rb = 0; rb < 8; ++rb) {
    if (FINAL) {
      float bv = bias[col];
#pragma unroll
      for (int reg = 0; reg < 16; ++reg) {
        int row = rb * 32 + (reg & 3) + 8 * (reg >> 2) + 4 * hi;
        float v = acc[rb][reg] + bv; v = v > 0.f ? v : 0.f;
        Cf[(size_t)row * NHID + col] = f2bf(v);
      }
    } else {
      float* base = Cp + (size_t)ks0 * 256 * NHID;
#pragma unroll
      for (int reg = 0; reg < 16; ++reg) {
        int row = rb * 32 + (reg & 3) + 8 * (reg >> 2) + 4 * hi;
        base[(size_t)row * NHID + col] = acc[rb][reg];
      }
    }
  }
}

// ---------------- reduce K-split partials: h2 = relu(sum_s part + bias) -> bf16 ----------------
__global__ void reduce_h2(const float* __restrict__ part, const float* __restrict__ bias,
                          unsigned short* __restrict__ h2, int S) {
  size_t g = ((size_t)blockIdx.x * 256 + threadIdx.x) * 4;
  int c = (int)(g % NHID);
  float4 s = *reinterpret_cast<const float4*>(part + g);
  for (int k = 1; k < S; ++k) {
    float4 p = *reinterpret_cast<const float4*>(part + (size_t)k * 256 * NHID + g);
    s.x += p.x; s.y += p.y; s.z += p.z; s.w += p.w;
  }
  float4 b = *reinterpret_cast<const float4*>(bias + c);
  s.x += b.x; s.y += b.y; s.z += b.z; s.w += b.w;
  us4 o;
  o[0] = f2bf(s.x > 0.f ? s.x : 0.f);
  o[1] = f2bf(s.y > 0.f ? s.y : 0.f);
  o[2] = f2bf(s.z > 0.f ? s.z : 0.f);
  o[3] = f2bf(s.w > 0.f ? s.w : 0.f);
  *reinterpret_cast<us4*>(h2 + g) = o;
}

// ---------------- fold Wout [15872][992] -> Wv [15872][32] ----------------
__global__ void wv_fold(const float* __restrict__ Wout, float* __restrict__ Wv) {
  int g = blockIdx.x * 256 + threadIdx.x;
  int k = g >> 5, c = g & 31;
  const float* row = Wout + (size_t)k * 992;
  float s = 0.f;
#pragma unroll
  for (int o = 0; o < 32; ++o) {
    if (o == c) continue;
    int i = c < o ? c : o;
    int j = c < o ? o : c;
    int p = 31 * i - (i * (i - 1)) / 2 + (j - i - 1);
    s += row[2 * p + (c > o ? 1 : 0)];
  }
  Wv[g] = s;
}

// ---------------- votes partial = h2 @ Wv, K-split 32 ----------------
__global__ void votes_partial(const unsigned short* __restrict__ h2,
                              const float* __restrict__ Wv,
                              float* __restrict__ part) {
  int bm = blockIdx.x >> 5;
  int ks = blockIdx.x & 31;
  int r  = bm * 8 + (threadIdx.x >> 5);
  int c  = threadIdx.x & 31;
  const unsigned short* hrow = h2 + (size_t)r * NHID + ks * 496;
  const float* wp = Wv + (size_t)(ks * 496) * 32 + c;
  float s = 0.f;
  for (int k0 = 0; k0 < 496; k0 += 8) {
    short8 hv = *reinterpret_cast<const short8*>(hrow + k0);
#pragma unroll
    for (int j = 0; j < 8; ++j)
      s += bf2f((unsigned short)hv[j]) * wp[(size_t)(k0 + j) * 32];
  }
  part[(size_t)(ks * 256 + r) * 32 + c] = s;
}

// ---------------- reduce votes + bias-fold ----------------
__global__ void votes_reduce(const float* __restrict__ part,
                             const float* __restrict__ bout,
                             float* __restrict__ out) {
  int g = blockIdx.x * 256 + threadIdx.x;
  int c = g & 31;
  float s = 0.f;
#pragma unroll
  for (int ks = 0; ks < 32; ++ks) s += part[(size_t)ks * 8192 + g];
  float bv = 0.f;
#pragma unroll
  for (int o = 0; o < 32; ++o) {
    if (o == c) continue;
    int i = c < o ? c : o;
    int j = c < o ? o : c;
    int p = 31 * i - (i * (i - 1)) / 2 + (j - i - 1);
    bv += bout[2 * p + (c > o ? 1 : 0)];
  }
  out[g] = s + bv;
}

extern "C" void kernel_launch(void* const* d_in, const int* in_sizes, int n_in,
                              void* d_out, int out_size, void* d_ws, size_t ws_size,
                              hipStream_t stream) {
  const float* x    = (const float*)d_in[0];
  const float* W1   = (const float*)d_in[1];
  const float* b1   = (const float*)d_in[2];
  const float* W2   = (const float*)d_in[3];
  const float* b2   = (const float*)d_in[4];
  const float* Wout = (const float*)d_in[5];
  const float* bout = (const float*)d_in[6];
  float* out = (float*)d_out;

  char* ws = (char*)d_ws;
  unsigned short* xb = (unsigned short*)(ws);                       // 262144
  unsigned short* h1 = (unsigned short*)(ws + 262144);              // 8126464
  unsigned short* h2 = (unsigned short*)(ws + 8388608);             // 8126464
  float*          Wv = (float*)(ws + 16515072);                     // 2031616
  float*        part = (float*)(ws + 18546688);                     // 1048576
  float*       part2 = (float*)(ws + 19595264);                     // 4*256*NHID*4

  const size_t PART1 = (size_t)256 * NHID * 4;
  const bool split4 = ws_size >= 19595264ull + 4 * PART1;

  hipLaunchKernelGGL(cvt_x, dim3(128), dim3(256), 0, stream, x, xb);
  hipLaunchKernelGGL((gemm_v8<true>), dim3(62, 1), dim3(512), 0, stream,
                     xb, 512, 512, W1, b1, h1, (float*)nullptr);
  if (split4) {
    hipLaunchKernelGGL((gemm_v8<false>), dim3(62, 4), dim3(512), 0, stream,
                       h1, NHID, NHID / 4, W2, (const float*)nullptr,
                       (unsigned short*)nullptr, part2);
    hipLaunchKernelGGL(reduce_h2, dim3(3968), dim3(256), 0, stream, part2, b2, h2, 4);
  } else {
    hipLaunchKernelGGL((gemm_v8<true>), dim3(62, 1), dim3(512), 0, stream,
                       h1, NHID, NHID, W2, b2, h2, (float*)nullptr);
  }
  hipLaunchKernelGGL(wv_fold,       dim3(1984), dim3(256), 0, stream, Wout, Wv);
  hipLaunchKernelGGL(votes_partial, dim3(1024), dim3(256), 0, stream, h2, Wv, part);
  hipLaunchKernelGGL(votes_reduce,  dim3(32),   dim3(256), 0, stream, part, bout, out);
}

// Round 9
// 418.154 us; speedup vs baseline: 2.0424x; 1.1749x over previous
//
#include <hip/hip_runtime.h>
#include <hip/hip_bf16.h>

using short8 = __attribute__((ext_vector_type(8))) short;
using f32x16 = __attribute__((ext_vector_type(16))) float;
using us4    = __attribute__((ext_vector_type(4))) unsigned short;

#define NHID 15872

__device__ __forceinline__ unsigned short f2bf(float f) {
  unsigned u = __builtin_bit_cast(unsigned, f);
  u += 0x7fff + ((u >> 16) & 1);          // RNE
  return (unsigned short)(u >> 16);
}
__device__ __forceinline__ short f2bf_hw(float f) {
  __hip_bfloat16 h = __float2bfloat16(f);
  return __builtin_bit_cast(short, h);
}
__device__ __forceinline__ float bf2f(unsigned short h) {
  return __builtin_bit_cast(float, ((unsigned)h) << 16);
}

// async global->LDS, 16B/lane. LDS dest = wave-uniform base + lane*16.
__device__ __forceinline__ void gload16(const void* g, void* l) {
  __builtin_amdgcn_global_load_lds(
      (const __attribute__((address_space(1))) unsigned int*)g,
      (__attribute__((address_space(3))) unsigned int*)l, 16, 0, 0);
}

// packed-A layout: tile gt (32 k), element (row, k): k=gt*32+i*16+sub*8+e
// short index = gt*8192 + i*4096 + (row + 256*sub)*8 + e   (matches LDS image)
__device__ __forceinline__ size_t pk_idx(int row, int col) {
  return (size_t)(col >> 5) * 8192 + (size_t)((col >> 4) & 1) * 4096 +
         (size_t)(row + 256 * ((col >> 3) & 1)) * 8 + (col & 7);
}

// ---------------- kernel 0: x fp32 -> packed bf16 ----------------
__global__ void cvt_x_pack(const float* __restrict__ x, unsigned short* __restrict__ xpk) {
  int g = blockIdx.x * 256 + threadIdx.x;       // 16384 chunks of 8
  int row = g >> 6, k0 = (g & 63) * 8;
  const float* p = x + (size_t)row * 512 + k0;
  float4 a = *reinterpret_cast<const float4*>(p);
  float4 b = *reinterpret_cast<const float4*>(p + 4);
  us4 o0, o1;
  o0[0] = f2bf(a.x); o0[1] = f2bf(a.y); o0[2] = f2bf(a.z); o0[3] = f2bf(a.w);
  o1[0] = f2bf(b.x); o1[1] = f2bf(b.y); o1[2] = f2bf(b.z); o1[3] = f2bf(b.w);
  unsigned short* d = xpk + pk_idx(row, k0);    // 8 shorts contiguous
  *reinterpret_cast<us4*>(d)     = o0;
  *reinterpret_cast<us4*>(d + 4) = o1;
}

// ---------------- main GEMM v9: counted-vmcnt ring, packed A ----------------
// BM=256 (all M), BN=256, BK=32. 512 thr = 8 waves; wave w owns cols w*32..+31,
// all 256 rows (acc = 8 x f32x16). 1 WG/CU, 3-deep LDS ring, vmcnt(12) waits.
// OUTMODE: 0 = bias+relu -> packed bf16 (GEMM1), 1 = fp32 partials (GEMM2 split),
//          2 = bias+relu -> row-major bf16 (fallback).

#define WAITV(N) asm volatile("s_waitcnt vmcnt(" #N ")" ::: "memory")

#define STAGE(BUF, T) do { \
    _Pragma("unroll") \
    for (int j_ = 0; j_ < 4; ++j_) \
      gload16(bsrc + ((size_t)(T) * 32 + j_ * 8) * NHID, \
              &Blds[BUF][(j_ * 8 + w) * 256]); \
    { \
      const unsigned short* as_ = apk_src + (size_t)(T) * 8192; \
      gload16(as_,        &Alds[BUF][w * 512]); \
      gload16(as_ + 4096, &Alds[BUF][4096 + w * 512]); \
    } \
  } while (0)

#define COMPUTE(BUF) do { \
    _Pragma("unroll") \
    for (int ks_ = 0; ks_ < 2; ++ks_) { \
      float bf_[8]; \
      _Pragma("unroll") \
      for (int jj_ = 0; jj_ < 8; ++jj_) \
        bf_[jj_] = Blds[BUF][(ks_ * 16 + hi * 8 + jj_) * 256 + w * 32 + l31]; \
      short8 bfr_; \
      _Pragma("unroll") \
      for (int jj_ = 0; jj_ < 8; ++jj_) bfr_[jj_] = f2bf_hw(bf_[jj_]); \
      _Pragma("unroll") \
      for (int rb_ = 0; rb_ < 8; ++rb_) { \
        short8 afr_ = *reinterpret_cast<const short8*>( \
            &Alds[BUF][ks_ * 4096 + (rb_ * 32 + l31 + 256 * hi) * 8]); \
        acc[rb_] = __builtin_amdgcn_mfma_f32_32x32x16_bf16(afr_, bfr_, acc[rb_], 0, 0, 0); \
      } \
    } \
  } while (0)

template<int OUTMODE>
__global__ __launch_bounds__(512, 2)
void gemm_v9(const unsigned short* __restrict__ Apk, int KC,
             const float* __restrict__ B, const float* __restrict__ bias,
             unsigned short* __restrict__ Cf, float* __restrict__ Cp)
{
  __shared__ float Blds[3][32 * 256];   // 96 KB: [buf][k][col] fp32, linear
  __shared__ short Alds[3][2 * 4096];   // 48 KB: [buf][i][row*8] bf16, packed image

  const int n0   = blockIdx.x * 256;
  const int ks0  = blockIdx.y;
  const int k0   = ks0 * KC;
  const int tid  = threadIdx.x;
  const int w    = tid >> 6;
  const int lane = tid & 63;
  const int l31  = lane & 31;
  const int hi   = lane >> 5;

  f32x16 acc[8] = {};

  // B src: row (k0 + t*32 + j*8 + w), cols n0 + lane*4..+3 (1 KB/wave-instr)
  const float* bsrc = B + (size_t)(k0 + w) * NHID + n0 + lane * 4;
  // A src: packed tiles, contiguous 1 KB/wave-instr
  const unsigned short* apk_src = Apk + (size_t)(k0 >> 5) * 8192 + tid * 8;

  const int NT = KC >> 5;

  STAGE(0, 0);
  if (NT > 1) STAGE(1, 1);
  if (NT > 2) STAGE(2, 2);
  int cur = 0;
  for (int t = 0; t < NT; ++t) {
    int rem = NT - 1 - t;
    if (rem >= 2)      WAITV(12);   // tiles t+1,t+2 stay in flight
    else if (rem == 1) WAITV(6);
    else               WAITV(0);
    __builtin_amdgcn_sched_barrier(0);
    __builtin_amdgcn_s_barrier();          // all waves' tile-t data in LDS
    COMPUTE(cur);
    __builtin_amdgcn_s_barrier();          // all waves done reading buf cur
    if (t + 3 < NT) STAGE(cur, t + 3);     // reuse buf, counted in vmcnt
    cur = (cur == 2) ? 0 : cur + 1;
  }

  // epilogue: verified mapping col = n0 + w*32 + l31, row = rb*32+(reg&3)+8*(reg>>2)+4*hi
  const int col = n0 + w * 32 + l31;
  const float bv = (OUTMODE != 1) ? bias[col] : 0.f;
#pragma unroll
  for (int rb = 0; rb < 8; ++rb) {
#pragma unroll
    for (int reg = 0; reg < 16; ++reg) {
      int row = rb * 32 + (reg & 3) + 8 * (reg >> 2) + 4 * hi;
      if (OUTMODE == 0) {
        float v = acc[rb][reg] + bv; v = v > 0.f ? v : 0.f;
        Cf[pk_idx(row, col)] = f2bf(v);
      } else if (OUTMODE == 1) {
        Cp[(size_t)ks0 * 256 * NHID + (size_t)row * NHID + col] = acc[rb][reg];
      } else {
        float v = acc[rb][reg] + bv; v = v > 0.f ? v : 0.f;
        Cf[(size_t)row * NHID + col] = f2bf(v);
      }
    }
  }
}

// ---------------- reduce K-split partials: h2 = relu(sum + bias) -> bf16 row-major ----------------
__global__ void reduce_h2(const float* __restrict__ part, const float* __restrict__ bias,
                          unsigned short* __restrict__ h2, int S) {
  size_t g = ((size_t)blockIdx.x * 256 + threadIdx.x) * 4;
  int c = (int)(g % NHID);
  float4 s = *reinterpret_cast<const float4*>(part + g);
  for (int k = 1; k < S; ++k) {
    float4 p = *reinterpret_cast<const float4*>(part + (size_t)k * 256 * NHID + g);
    s.x += p.x; s.y += p.y; s.z += p.z; s.w += p.w;
  }
  float4 b = *reinterpret_cast<const float4*>(bias + c);
  s.x += b.x; s.y += b.y; s.z += b.z; s.w += b.w;
  us4 o;
  o[0] = f2bf(s.x > 0.f ? s.x : 0.f);
  o[1] = f2bf(s.y > 0.f ? s.y : 0.f);
  o[2] = f2bf(s.z > 0.f ? s.z : 0.f);
  o[3] = f2bf(s.w > 0.f ? s.w : 0.f);
  *reinterpret_cast<us4*>(h2 + g) = o;
}

// ---------------- fold Wout [15872][992] -> Wv [15872][32] ----------------
__global__ void wv_fold(const float* __restrict__ Wout, float* __restrict__ Wv) {
  int g = blockIdx.x * 256 + threadIdx.x;
  int k = g >> 5, c = g & 31;
  const float* row = Wout + (size_t)k * 992;
  float s = 0.f;
#pragma unroll
  for (int o = 0; o < 32; ++o) {
    if (o == c) continue;
    int i = c < o ? c : o;
    int j = c < o ? o : c;
    int p = 31 * i - (i * (i - 1)) / 2 + (j - i - 1);
    s += row[2 * p + (c > o ? 1 : 0)];
  }
  Wv[g] = s;
}

// ---------------- votes partial = h2 @ Wv, K-split 32 ----------------
__global__ void votes_partial(const unsigned short* __restrict__ h2,
                              const float* __restrict__ Wv,
                              float* __restrict__ part) {
  int bm = blockIdx.x >> 5;
  int ks = blockIdx.x & 31;
  int r  = bm * 8 + (threadIdx.x >> 5);
  int c  = threadIdx.x & 31;
  const unsigned short* hrow = h2 + (size_t)r * NHID + ks * 496;
  const float* wp = Wv + (size_t)(ks * 496) * 32 + c;
  float s = 0.f;
  for (int k0 = 0; k0 < 496; k0 += 8) {
    short8 hv = *reinterpret_cast<const short8*>(hrow + k0);
#pragma unroll
    for (int j = 0; j < 8; ++j)
      s += bf2f((unsigned short)hv[j]) * wp[(size_t)(k0 + j) * 32];
  }
  part[(size_t)(ks * 256 + r) * 32 + c] = s;
}

// ---------------- reduce votes + bias-fold ----------------
__global__ void votes_reduce(const float* __restrict__ part,
                             const float* __restrict__ bout,
                             float* __restrict__ out) {
  int g = blockIdx.x * 256 + threadIdx.x;
  int c = g & 31;
  float s = 0.f;
#pragma unroll
  for (int ks = 0; ks < 32; ++ks) s += part[(size_t)ks * 8192 + g];
  float bv = 0.f;
#pragma unroll
  for (int o = 0; o < 32; ++o) {
    if (o == c) continue;
    int i = c < o ? c : o;
    int j = c < o ? o : c;
    int p = 31 * i - (i * (i - 1)) / 2 + (j - i - 1);
    bv += bout[2 * p + (c > o ? 1 : 0)];
  }
  out[g] = s + bv;
}

extern "C" void kernel_launch(void* const* d_in, const int* in_sizes, int n_in,
                              void* d_out, int out_size, void* d_ws, size_t ws_size,
                              hipStream_t stream) {
  const float* x    = (const float*)d_in[0];
  const float* W1   = (const float*)d_in[1];
  const float* b1   = (const float*)d_in[2];
  const float* W2   = (const float*)d_in[3];
  const float* b2   = (const float*)d_in[4];
  const float* Wout = (const float*)d_in[5];
  const float* bout = (const float*)d_in[6];
  float* out = (float*)d_out;

  char* ws = (char*)d_ws;
  unsigned short* xpk  = (unsigned short*)(ws);                     // 262144
  unsigned short* h1pk = (unsigned short*)(ws + 262144);            // 8126464
  unsigned short* h2   = (unsigned short*)(ws + 8388608);           // 8126464
  float*          Wv   = (float*)(ws + 16515072);                   // 2031616
  float*          part = (float*)(ws + 18546688);                   // 1048576
  float*         part2 = (float*)(ws + 19595264);                   // 4*256*NHID*4

  const size_t PART1 = (size_t)256 * NHID * 4;
  const bool split4 = ws_size >= 19595264ull + 4 * PART1;

  hipLaunchKernelGGL(cvt_x_pack, dim3(64), dim3(256), 0, stream, x, xpk);
  // GEMM1: K=512, packed-A in, packed bf16 out (bias+relu)
  hipLaunchKernelGGL((gemm_v9<0>), dim3(62, 1), dim3(512), 0, stream,
                     xpk, 512, W1, b1, h1pk, (float*)nullptr);
  if (split4) {
    hipLaunchKernelGGL((gemm_v9<1>), dim3(62, 4), dim3(512), 0, stream,
                       h1pk, NHID / 4, W2, (const float*)nullptr,
                       (unsigned short*)nullptr, part2);
    hipLaunchKernelGGL(reduce_h2, dim3(3968), dim3(256), 0, stream, part2, b2, h2, 4);
  } else {
    hipLaunchKernelGGL((gemm_v9<2>), dim3(62, 1), dim3(512), 0, stream,
                       h1pk, NHID, W2, b2, h2, (float*)nullptr);
  }
  hipLaunchKernelGGL(wv_fold,       dim3(1984), dim3(256), 0, stream, Wout, Wv);
  hipLaunchKernelGGL(votes_partial, dim3(1024), dim3(256), 0, stream, h2, Wv, part);
  hipLaunchKernelGGL(votes_reduce,  dim3(32),   dim3(256), 0, stream, part, bout, out);
}